// Round 5
// baseline (1876.902 us; speedup 1.0000x reference)
//
#include <hip/hip_runtime.h>
#include <hip/hip_bf16.h>

#define NTOK 49
#define NB 2048
#define SCALE 0.17677669529663687f  // 32^-0.5

typedef __attribute__((ext_vector_type(8))) short short8;
typedef __attribute__((ext_vector_type(4))) float f32x4;
typedef __attribute__((ext_vector_type(4))) unsigned short u16x4;

static __device__ __forceinline__ unsigned short f2bf(float f) {
    union { float f; unsigned int u; } v; v.f = f;
    unsigned int r = v.u + 0x7FFFu + ((v.u >> 16) & 1u);
    return (unsigned short)(r >> 16);
}

static __device__ __forceinline__ unsigned int pkbf(float lo, float hi) {
    __hip_bfloat162 h = __float22bfloat162_rn(make_float2(lo, hi));  // .x -> low16
    union { __hip_bfloat162 h; unsigned int u; } c; c.h = h; return c.u;
}

// g-axis repack: source C/D regs (row = 16*mt + 4*g' + r) -> frag (k-elem = 8*g + j).
static __device__ __forceinline__ short8 repack(const unsigned int* pkA, const unsigned int* pkB,
                                                int lid, int g) {
    int sA = lid + ((2 * (g & 1)) << 4);
    int sB = sA + 16;
    unsigned int l0 = __shfl((int)pkA[0], sA), h0 = __shfl((int)pkB[0], sA);
    unsigned int l1 = __shfl((int)pkA[1], sA), h1 = __shfl((int)pkB[1], sA);
    unsigned int l2 = __shfl((int)pkA[0], sB), h2 = __shfl((int)pkB[0], sB);
    unsigned int l3 = __shfl((int)pkA[1], sB), h3 = __shfl((int)pkB[1], sB);
    bool hi = (g & 2);
    union { short8 s; unsigned int u[4]; } r;
    r.u[0] = hi ? h0 : l0;
    r.u[1] = hi ? h1 : l1;
    r.u[2] = hi ? h2 : l2;
    r.u[3] = hi ? h3 : l3;
    return r.s;
}

// ---- workspace layout (bytes) ----
#define MW_ELEMS (64 * 64 * 64)              // mask fp32 [w][q 64][k 64], -1e30 pad
#define RH_ELEMS (12 * 64 * 64)              // rpb  fp32 [h][q 64][k 64], 0 pad
#define MW_OFF 0
#define RH_OFF (MW_ELEMS * 4)
#define WTQ_OFF (RH_OFF + RH_ELEMS * 4)
#define WTQ_ELEMS (1152 * 384)               // W_qkv^T bf16 [col][k]
#define BQ_OFF (WTQ_OFF + WTQ_ELEMS * 2)     // scaled qkv bias fp32 [1152]
#define WTP_OFF (BQ_OFF + 1152 * 4)          // W_proj^T bf16 [384][384]
#define WTP_ELEMS (384 * 384)

__global__ __launch_bounds__(256) void wa_prep(
    const float* __restrict__ mask, const float* __restrict__ qkv_w,
    const float* __restrict__ qkv_b, const float* __restrict__ rpb,
    const float* __restrict__ proj_w, unsigned char* __restrict__ ws)
{
    float* Mw = (float*)(ws + MW_OFF);
    float* Rh = (float*)(ws + RH_OFF);
    unsigned short* wtq = (unsigned short*)(ws + WTQ_OFF);
    float* bq = (float*)(ws + BQ_OFF);
    unsigned short* wtp = (unsigned short*)(ws + WTP_OFF);
    const int TOT = MW_ELEMS + RH_ELEMS + WTQ_ELEMS + 1152 + WTP_ELEMS;
    for (int idx = blockIdx.x * 256 + threadIdx.x; idx < TOT; idx += gridDim.x * 256) {
        if (idx < MW_ELEMS) {
            int m = idx & 63, n = (idx >> 6) & 63, w = idx >> 12;
            Mw[idx] = (n < NTOK && m < NTOK) ? mask[(w * NTOK + n) * NTOK + m] : -1e30f;
        } else if (idx < MW_ELEMS + RH_ELEMS) {
            int t = idx - MW_ELEMS;
            int m = t & 63, n = (t >> 6) & 63, h = t >> 12;
            float v = 0.f;
            if (n < NTOK && m < NTOK) {
                int ni = n / 7, nj = n % 7, mi = m / 7, mj = m % 7;
                int ridx = (ni - mi + 6) * 13 + (nj - mj + 6);
                v = rpb[ridx * 12 + h];
            }
            Rh[t] = v;
        } else if (idx < MW_ELEMS + RH_ELEMS + WTQ_ELEMS) {
            int t = idx - MW_ELEMS - RH_ELEMS;
            int j = t / 384, k = t - j * 384;
            float s = (j < 384) ? SCALE : 1.0f;
            wtq[t] = f2bf(qkv_w[k * 1152 + j] * s);
        } else if (idx < MW_ELEMS + RH_ELEMS + WTQ_ELEMS + 1152) {
            int j = idx - MW_ELEMS - RH_ELEMS - WTQ_ELEMS;
            bq[j] = qkv_b[j] * ((j < 384) ? SCALE : 1.0f);
        } else {
            int t = idx - MW_ELEMS - RH_ELEMS - WTQ_ELEMS - 1152;
            int j = t / 384, k = t - j * 384;
            wtp[t] = f2bf(proj_w[k * 384 + j]);
        }
    }
}

// Fused per-window kernel, 4 waves x 3 heads.
// LDS = X[49][396] bf16 only (38808 B) -> 4 blocks/CU (VGPR pinned <=128 via launch_bounds).
// AO exchanged via the block's OWN out-slice 2nd half as bf16 [head][token][32d]:
// O^T = mfma(vf, pf) puts 4 consecutive d per lane -> packed uint2 global stores,
// full-line per-head regions (no partial-line churn), perfect 16B A-frag reads in proj.
__global__ __launch_bounds__(256, 4) void wa_main(
    const float* __restrict__ x, const float* __restrict__ bproj,
    const unsigned char* __restrict__ ws, float* __restrict__ out)
{
    __shared__ unsigned short X[49 * 396];

    const float* Mw = (const float*)(ws + MW_OFF);
    const float* Rh = (const float*)(ws + RH_OFF);
    const unsigned short* wtq = (const unsigned short*)(ws + WTQ_OFF);
    const float* bq = (const float*)(ws + BQ_OFF);
    const unsigned short* wtp = (const unsigned short*)(ws + WTP_OFF);

    const int tid = threadIdx.x;
    const int b = blockIdx.x;
    const int w64 = b & 63;
    const int wv = tid >> 6;
    const int lane = tid & 63;
    const int lid = lane & 15;
    const int g = lane >> 4;

    // ---- stage x (49 rows) as bf16, pitch 396 (conflict-free: 198 dwords == 6 mod 32) ----
    const float4* xw = (const float4*)(x + (size_t)b * (NTOK * 384));
    for (int i = tid; i < NTOK * 96; i += 256) {
        float4 v = xw[i];
        int row = i / 96, col = (i - row * 96) * 4;
        u16x4 o;
        o.x = f2bf(v.x); o.y = f2bf(v.y); o.z = f2bf(v.z); o.w = f2bf(v.w);
        *(u16x4*)&X[row * 396 + col] = o;
    }
    __syncthreads();

    // AO scratch: 2nd half of this block's own out slice (byte off b*75264 + 37632, 128B-aligned)
    unsigned short* aow = (unsigned short*)(out + (size_t)b * 18816 + 9408);

    int xoff[4];
    #pragma unroll
    for (int t = 0; t < 4; t++) {
        int row = 16 * t + lid; if (row > 48) row = 48;
        xoff[t] = row * 396 + g * 8;
    }

    for (int hh = 0; hh < 3; hh++) {
        const int h = wv * 3 + hh;
        const unsigned short* wqp = wtq + (size_t)(h * 32 + lid) * 384 + g * 8;
        const unsigned short* wkp = wtq + (size_t)(384 + h * 32 + lid) * 384 + g * 8;
        const unsigned short* wvp = wtq + (size_t)(768 + h * 32 + lid) * 384 + g * 8;

        // ---- fused QKV: Q^T,K^T (M=32 d, N=64 tok), V (M=64 tok, N=32 d), K=384 ----
        f32x4 qa[2][4], ka[2][4], va[4][2];
        {
            f32x4 bqv[2], bkv[2];
            #pragma unroll
            for (int mt = 0; mt < 2; mt++) {
                bqv[mt] = *(const f32x4*)(bq + h * 32 + 16 * mt + 4 * g);
                bkv[mt] = *(const f32x4*)(bq + 384 + h * 32 + 16 * mt + 4 * g);
            }
            #pragma unroll
            for (int mt = 0; mt < 2; mt++)
                #pragma unroll
                for (int nt = 0; nt < 4; nt++) { qa[mt][nt] = bqv[mt]; ka[mt][nt] = bkv[mt]; }
            #pragma unroll
            for (int nt = 0; nt < 2; nt++) {
                float bv = bq[768 + h * 32 + 16 * nt + lid];
                #pragma unroll
                for (int mt = 0; mt < 4; mt++) va[mt][nt] = (f32x4){bv, bv, bv, bv};
            }
        }
        for (int kk = 0; kk < 12; kk++) {
            short8 xb[4], wq[2], wk[2], wvf[2];
            #pragma unroll
            for (int t = 0; t < 4; t++) xb[t] = *(const short8*)&X[xoff[t] + kk * 32];
            #pragma unroll
            for (int mt = 0; mt < 2; mt++) {
                wq[mt] = *(const short8*)(wqp + (size_t)(16 * mt) * 384 + kk * 32);
                wk[mt] = *(const short8*)(wkp + (size_t)(16 * mt) * 384 + kk * 32);
                wvf[mt] = *(const short8*)(wvp + (size_t)(16 * mt) * 384 + kk * 32);
            }
            __builtin_amdgcn_s_setprio(1);
            #pragma unroll
            for (int mt = 0; mt < 2; mt++)
                #pragma unroll
                for (int nt = 0; nt < 4; nt++) {
                    qa[mt][nt] = __builtin_amdgcn_mfma_f32_16x16x32_bf16(wq[mt], xb[nt], qa[mt][nt], 0, 0, 0);
                    ka[mt][nt] = __builtin_amdgcn_mfma_f32_16x16x32_bf16(wk[mt], xb[nt], ka[mt][nt], 0, 0, 0);
                }
            #pragma unroll
            for (int mt = 0; mt < 4; mt++)
                #pragma unroll
                for (int nt = 0; nt < 2; nt++)
                    va[mt][nt] = __builtin_amdgcn_mfma_f32_16x16x32_bf16(xb[mt], wvf[nt], va[mt][nt], 0, 0, 0);
            __builtin_amdgcn_s_setprio(0);
        }

        // ---- repack to fragments ----
        short8 qf[4], kf[4], vf[2][2];
        #pragma unroll
        for (int nt = 0; nt < 4; nt++) {
            unsigned int p0[2] = { pkbf(qa[0][nt][0], qa[0][nt][1]), pkbf(qa[0][nt][2], qa[0][nt][3]) };
            unsigned int p1[2] = { pkbf(qa[1][nt][0], qa[1][nt][1]), pkbf(qa[1][nt][2], qa[1][nt][3]) };
            qf[nt] = repack(p0, p1, lid, g);
            unsigned int k0[2] = { pkbf(ka[0][nt][0], ka[0][nt][1]), pkbf(ka[0][nt][2], ka[0][nt][3]) };
            unsigned int k1[2] = { pkbf(ka[1][nt][0], ka[1][nt][1]), pkbf(ka[1][nt][2], ka[1][nt][3]) };
            kf[nt] = repack(k0, k1, lid, g);
        }
        #pragma unroll
        for (int nt = 0; nt < 2; nt++) {
            unsigned int pv[4][2];
            #pragma unroll
            for (int mt = 0; mt < 4; mt++) {
                pv[mt][0] = pkbf(va[mt][nt][0], va[mt][nt][1]);
                pv[mt][1] = pkbf(va[mt][nt][2], va[mt][nt][3]);
            }
            vf[0][nt] = repack(pv[0], pv[1], lid, g);
            vf[1][nt] = repack(pv[2], pv[3], lid, g);
        }

        // ---- S^T = K·Q^T : D[k-tok][q-tok]  (16 MFMA, K=32) ----
        f32x4 S[4][4];  // [kt][qt]
        __builtin_amdgcn_s_setprio(1);
        #pragma unroll
        for (int kt = 0; kt < 4; kt++)
            #pragma unroll
            for (int qt = 0; qt < 4; qt++)
                S[kt][qt] = __builtin_amdgcn_mfma_f32_16x16x32_bf16(kf[kt], qf[qt], (f32x4){0.f, 0.f, 0.f, 0.f}, 0, 0, 0);
        __builtin_amdgcn_s_setprio(0);

        // ---- bias (mask + rpb, both L2-resident) + softmax over k; normalize P ----
        const float* mwp = Mw + (size_t)w64 * 4096;
        const float* rhp = Rh + (size_t)h * 4096;
        short8 pf[4][2];
        #pragma unroll
        for (int qt = 0; qt < 4; qt++) {
            #pragma unroll
            for (int kt = 0; kt < 4; kt++) {
                int off = (16 * qt + lid) * 64 + 16 * kt + 4 * g;
                S[kt][qt] += *(const f32x4*)(mwp + off) + *(const f32x4*)(rhp + off);
            }
            float mx = S[0][qt][0];
            #pragma unroll
            for (int kt = 0; kt < 4; kt++)
                #pragma unroll
                for (int r = 0; r < 4; r++) mx = fmaxf(mx, S[kt][qt][r]);
            mx = fmaxf(mx, __shfl_xor(mx, 16));
            mx = fmaxf(mx, __shfl_xor(mx, 32));
            float sm = 0.f;
            #pragma unroll
            for (int kt = 0; kt < 4; kt++)
                #pragma unroll
                for (int r = 0; r < 4; r++) {
                    float e = __expf(S[kt][qt][r] - mx);
                    S[kt][qt][r] = e; sm += e;
                }
            sm += __shfl_xor(sm, 16);
            sm += __shfl_xor(sm, 32);
            float rv = 1.0f / sm;
            unsigned int pp[4][2];
            #pragma unroll
            for (int kt = 0; kt < 4; kt++) {
                pp[kt][0] = pkbf(S[kt][qt][0] * rv, S[kt][qt][1] * rv);
                pp[kt][1] = pkbf(S[kt][qt][2] * rv, S[kt][qt][3] * rv);
            }
            pf[qt][0] = repack(pp[0], pp[1], lid, g);
            pf[qt][1] = repack(pp[2], pp[3], lid, g);
        }

        // ---- O^T = V^T·P^T : D[d][q-tok]  (operand-swapped PV; same 16 MFMA) ----
        f32x4 OT[2][4];  // [dt][qt]: col = q-token = lid, row = d = 16dt+4g+r
        #pragma unroll
        for (int dt = 0; dt < 2; dt++)
            #pragma unroll
            for (int qt = 0; qt < 4; qt++) OT[dt][qt] = (f32x4){0.f,0.f,0.f,0.f};
        __builtin_amdgcn_s_setprio(1);
        #pragma unroll
        for (int kb = 0; kb < 2; kb++)
            #pragma unroll
            for (int dt = 0; dt < 2; dt++)
                #pragma unroll
                for (int qt = 0; qt < 4; qt++)
                    OT[dt][qt] = __builtin_amdgcn_mfma_f32_16x16x32_bf16(vf[kb][dt], pf[qt][kb], OT[dt][qt], 0, 0, 0);
        __builtin_amdgcn_s_setprio(0);

        // ---- store AO bf16 [head][token][32 d]: 8B per lane, contiguous full lines ----
        #pragma unroll
        for (int qt = 0; qt < 4; qt++) {
            int token = 16 * qt + lid;
            if (token < NTOK) {
                #pragma unroll
                for (int dt = 0; dt < 2; dt++) {
                    unsigned int lo = pkbf(OT[dt][qt][0], OT[dt][qt][1]);
                    unsigned int hi = pkbf(OT[dt][qt][2], OT[dt][qt][3]);
                    *(uint2*)(aow + (h * NTOK + token) * 32 + 16 * dt + 4 * g) = make_uint2(lo, hi);
                }
            }
        }
    }

    __threadfence_block();
    __syncthreads();

    // ---- proj: [49x384] @ Wt_proj + b; wave owns 96 cols; A-frags from AO scratch ----
    {
        const int c0 = wv * 96;
        f32x4 acc[4][6];
        #pragma unroll
        for (int nt = 0; nt < 6; nt++) {
            float bv = bproj[c0 + nt * 16 + lid];
            #pragma unroll
            for (int mt = 0; mt < 4; mt++) acc[mt][nt] = (f32x4){bv, bv, bv, bv};
        }
        #pragma unroll
        for (int kk = 0; kk < 12; kk++) {   // kk == head index; k = kk*32 + g*8 ..
            short8 a[4], bf[6];
            #pragma unroll
            for (int mt = 0; mt < 4; mt++) {
                int row = lid + 16 * mt;
                if (row > 48) row = 48;
                a[mt] = *(const short8*)(aow + (kk * NTOK + row) * 32 + g * 8);
            }
            #pragma unroll
            for (int nt = 0; nt < 6; nt++)
                bf[nt] = *(const short8*)(wtp + (size_t)(c0 + nt * 16 + lid) * 384 + kk * 32 + g * 8);
            __builtin_amdgcn_s_setprio(1);
            #pragma unroll
            for (int mt = 0; mt < 4; mt++)
                #pragma unroll
                for (int nt = 0; nt < 6; nt++)
                    acc[mt][nt] = __builtin_amdgcn_mfma_f32_16x16x32_bf16(a[mt], bf[nt], acc[mt][nt], 0, 0, 0);
            __builtin_amdgcn_s_setprio(0);
        }
        __syncthreads();   // all AO reads complete before in-place fp32 stores
        float* outb = out + (size_t)b * 18816;
        #pragma unroll
        for (int mt = 0; mt < 4; mt++)
            #pragma unroll
            for (int nt = 0; nt < 6; nt++)
                #pragma unroll
                for (int r = 0; r < 4; r++) {
                    int n = g * 4 + r + 16 * mt;
                    if (n < NTOK)
                        outb[n * 384 + c0 + nt * 16 + lid] = acc[mt][nt][r];
                }
    }
}

extern "C" void kernel_launch(void* const* d_in, const int* in_sizes, int n_in,
                              void* d_out, int out_size, void* d_ws, size_t ws_size,
                              hipStream_t stream) {
    const float* x      = (const float*)d_in[0];
    const float* mask   = (const float*)d_in[1];
    const float* qkv_w  = (const float*)d_in[2];
    const float* qkv_b  = (const float*)d_in[3];
    const float* rpb    = (const float*)d_in[4];
    const float* proj_w = (const float*)d_in[5];
    const float* proj_b = (const float*)d_in[6];
    unsigned char* ws = (unsigned char*)d_ws;

    wa_prep<<<dim3(1024), dim3(256), 0, stream>>>(mask, qkv_w, qkv_b, rpb, proj_w, ws);
    wa_main<<<dim3(NB), dim3(256), 0, stream>>>(x, proj_b, ws, (float*)d_out);
}

// Round 6
// 465.800 us; speedup vs baseline: 4.0294x; 4.0294x over previous
//
#include <hip/hip_runtime.h>
#include <hip/hip_bf16.h>

#define NTOK 49
#define NB 2048
#define SCALE 0.17677669529663687f  // 32^-0.5

typedef __attribute__((ext_vector_type(8))) short short8;
typedef __attribute__((ext_vector_type(4))) float f32x4;
typedef __attribute__((ext_vector_type(4))) unsigned short u16x4;

static __device__ __forceinline__ unsigned short f2bf(float f) {
    union { float f; unsigned int u; } v; v.f = f;
    unsigned int r = v.u + 0x7FFFu + ((v.u >> 16) & 1u);
    return (unsigned short)(r >> 16);
}

static __device__ __forceinline__ unsigned int pkbf(float lo, float hi) {
    __hip_bfloat162 h = __float22bfloat162_rn(make_float2(lo, hi));  // .x -> low16
    union { __hip_bfloat162 h; unsigned int u; } c; c.h = h; return c.u;
}

// g-axis repack: source C/D regs (row = 16*mt + 4*g' + r) -> frag (k-elem = 8*g + j).
static __device__ __forceinline__ short8 repack(const unsigned int* pkA, const unsigned int* pkB,
                                                int lid, int g) {
    int sA = lid + ((2 * (g & 1)) << 4);
    int sB = sA + 16;
    unsigned int l0 = __shfl((int)pkA[0], sA), h0 = __shfl((int)pkB[0], sA);
    unsigned int l1 = __shfl((int)pkA[1], sA), h1 = __shfl((int)pkB[1], sA);
    unsigned int l2 = __shfl((int)pkA[0], sB), h2 = __shfl((int)pkB[0], sB);
    unsigned int l3 = __shfl((int)pkA[1], sB), h3 = __shfl((int)pkB[1], sB);
    bool hi = (g & 2);
    union { short8 s; unsigned int u[4]; } r;
    r.u[0] = hi ? h0 : l0;
    r.u[1] = hi ? h1 : l1;
    r.u[2] = hi ? h2 : l2;
    r.u[3] = hi ? h3 : l3;
    return r.s;
}

// ---- workspace layout (bytes) ----
#define MW_ELEMS (64 * 64 * 64)              // mask fp32 [w][q 64][k 64], -1e30 pad
#define RH_ELEMS (12 * 64 * 64)              // rpb  fp32 [h][q 64][k 64], 0 pad
#define MW_OFF 0
#define RH_OFF (MW_ELEMS * 4)
#define WTQ_OFF (RH_OFF + RH_ELEMS * 4)
#define WTQ_ELEMS (1152 * 384)               // W_qkv^T bf16 [col][k]
#define BQ_OFF (WTQ_OFF + WTQ_ELEMS * 2)     // scaled qkv bias fp32 [1152]
#define WTP_OFF (BQ_OFF + 1152 * 4)          // W_proj^T bf16 [384][384]
#define WTP_ELEMS (384 * 384)

__global__ __launch_bounds__(256) void wa_prep(
    const float* __restrict__ mask, const float* __restrict__ qkv_w,
    const float* __restrict__ qkv_b, const float* __restrict__ rpb,
    const float* __restrict__ proj_w, unsigned char* __restrict__ ws)
{
    float* Mw = (float*)(ws + MW_OFF);
    float* Rh = (float*)(ws + RH_OFF);
    unsigned short* wtq = (unsigned short*)(ws + WTQ_OFF);
    float* bq = (float*)(ws + BQ_OFF);
    unsigned short* wtp = (unsigned short*)(ws + WTP_OFF);
    const int TOT = MW_ELEMS + RH_ELEMS + WTQ_ELEMS + 1152 + WTP_ELEMS;
    for (int idx = blockIdx.x * 256 + threadIdx.x; idx < TOT; idx += gridDim.x * 256) {
        if (idx < MW_ELEMS) {
            int m = idx & 63, n = (idx >> 6) & 63, w = idx >> 12;
            Mw[idx] = (n < NTOK && m < NTOK) ? mask[(w * NTOK + n) * NTOK + m] : -1e30f;
        } else if (idx < MW_ELEMS + RH_ELEMS) {
            int t = idx - MW_ELEMS;
            int m = t & 63, n = (t >> 6) & 63, h = t >> 12;
            float v = 0.f;
            if (n < NTOK && m < NTOK) {
                int ni = n / 7, nj = n % 7, mi = m / 7, mj = m % 7;
                int ridx = (ni - mi + 6) * 13 + (nj - mj + 6);
                v = rpb[ridx * 12 + h];
            }
            Rh[t] = v;
        } else if (idx < MW_ELEMS + RH_ELEMS + WTQ_ELEMS) {
            int t = idx - MW_ELEMS - RH_ELEMS;
            int j = t / 384, k = t - j * 384;
            float s = (j < 384) ? SCALE : 1.0f;
            wtq[t] = f2bf(qkv_w[k * 1152 + j] * s);
        } else if (idx < MW_ELEMS + RH_ELEMS + WTQ_ELEMS + 1152) {
            int j = idx - MW_ELEMS - RH_ELEMS - WTQ_ELEMS;
            bq[j] = qkv_b[j] * ((j < 384) ? SCALE : 1.0f);
        } else {
            int t = idx - MW_ELEMS - RH_ELEMS - WTQ_ELEMS - 1152;
            int j = t / 384, k = t - j * 384;
            wtp[t] = f2bf(proj_w[k * 384 + j]);
        }
    }
}

// Fused per-window kernel, 4 waves x 3 heads.
// LDS = X[49][396] bf16 only (38808 B). QKV split into QK pass + V pass so peak
// unified VGPR+AGPR stays ~130 (R5 lesson: (256,4) forced arch=64 + scratch spills,
// 6 GB traffic). launch_bounds (256,3) is a no-spill floor; if alloc <=128 the HW
// gives 4 blocks/CU anyway.
__global__ __launch_bounds__(256, 3) void wa_main(
    const float* __restrict__ x, const float* __restrict__ bproj,
    const unsigned char* __restrict__ ws, float* __restrict__ out)
{
    __shared__ unsigned short X[49 * 396];

    const float* Mw = (const float*)(ws + MW_OFF);
    const float* Rh = (const float*)(ws + RH_OFF);
    const unsigned short* wtq = (const unsigned short*)(ws + WTQ_OFF);
    const float* bq = (const float*)(ws + BQ_OFF);
    const unsigned short* wtp = (const unsigned short*)(ws + WTP_OFF);

    const int tid = threadIdx.x;
    const int b = blockIdx.x;
    const int w64 = b & 63;
    const int wv = tid >> 6;
    const int lane = tid & 63;
    const int lid = lane & 15;
    const int g = lane >> 4;

    // ---- stage x (49 rows) as bf16, pitch 396 ----
    const float4* xw = (const float4*)(x + (size_t)b * (NTOK * 384));
    for (int i = tid; i < NTOK * 96; i += 256) {
        float4 v = xw[i];
        int row = i / 96, col = (i - row * 96) * 4;
        u16x4 o;
        o.x = f2bf(v.x); o.y = f2bf(v.y); o.z = f2bf(v.z); o.w = f2bf(v.w);
        *(u16x4*)&X[row * 396 + col] = o;
    }
    __syncthreads();

    // AO scratch: 2nd half of this block's own out slice (bf16 [head][token][32d])
    unsigned short* aow = (unsigned short*)(out + (size_t)b * 18816 + 9408);

    int xoff[4];
    #pragma unroll
    for (int t = 0; t < 4; t++) {
        int row = 16 * t + lid; if (row > 48) row = 48;
        xoff[t] = row * 396 + g * 8;
    }

    for (int hh = 0; hh < 3; hh++) {
        const int h = wv * 3 + hh;
        const unsigned short* wqp = wtq + (size_t)(h * 32 + lid) * 384 + g * 8;
        const unsigned short* wkp = wtq + (size_t)(384 + h * 32 + lid) * 384 + g * 8;
        const unsigned short* wvp = wtq + (size_t)(768 + h * 32 + lid) * 384 + g * 8;

        short8 qf[4], kf[4], vf[2][2];

        // ---- pass 1: Q^T,K^T (M=32 d, N=64 tok), K=384 ----
        {
            f32x4 qa[2][4], ka[2][4];
            #pragma unroll
            for (int mt = 0; mt < 2; mt++) {
                f32x4 bqv = *(const f32x4*)(bq + h * 32 + 16 * mt + 4 * g);
                f32x4 bkv = *(const f32x4*)(bq + 384 + h * 32 + 16 * mt + 4 * g);
                #pragma unroll
                for (int nt = 0; nt < 4; nt++) { qa[mt][nt] = bqv; ka[mt][nt] = bkv; }
            }
            for (int kk = 0; kk < 12; kk++) {
                short8 xb[4], wq[2], wk[2];
                #pragma unroll
                for (int t = 0; t < 4; t++) xb[t] = *(const short8*)&X[xoff[t] + kk * 32];
                #pragma unroll
                for (int mt = 0; mt < 2; mt++) {
                    wq[mt] = *(const short8*)(wqp + (size_t)(16 * mt) * 384 + kk * 32);
                    wk[mt] = *(const short8*)(wkp + (size_t)(16 * mt) * 384 + kk * 32);
                }
                __builtin_amdgcn_s_setprio(1);
                #pragma unroll
                for (int mt = 0; mt < 2; mt++)
                    #pragma unroll
                    for (int nt = 0; nt < 4; nt++) {
                        qa[mt][nt] = __builtin_amdgcn_mfma_f32_16x16x32_bf16(wq[mt], xb[nt], qa[mt][nt], 0, 0, 0);
                        ka[mt][nt] = __builtin_amdgcn_mfma_f32_16x16x32_bf16(wk[mt], xb[nt], ka[mt][nt], 0, 0, 0);
                    }
                __builtin_amdgcn_s_setprio(0);
            }
            #pragma unroll
            for (int nt = 0; nt < 4; nt++) {
                unsigned int p0[2] = { pkbf(qa[0][nt][0], qa[0][nt][1]), pkbf(qa[0][nt][2], qa[0][nt][3]) };
                unsigned int p1[2] = { pkbf(qa[1][nt][0], qa[1][nt][1]), pkbf(qa[1][nt][2], qa[1][nt][3]) };
                qf[nt] = repack(p0, p1, lid, g);
                unsigned int k0[2] = { pkbf(ka[0][nt][0], ka[0][nt][1]), pkbf(ka[0][nt][2], ka[0][nt][3]) };
                unsigned int k1[2] = { pkbf(ka[1][nt][0], ka[1][nt][1]), pkbf(ka[1][nt][2], ka[1][nt][3]) };
                kf[nt] = repack(k0, k1, lid, g);
            }
        }

        // ---- pass 2: V (M=64 tok, N=32 d), K=384 ----
        {
            f32x4 va[4][2];
            #pragma unroll
            for (int nt = 0; nt < 2; nt++) {
                float bv = bq[768 + h * 32 + 16 * nt + lid];
                #pragma unroll
                for (int mt = 0; mt < 4; mt++) va[mt][nt] = (f32x4){bv, bv, bv, bv};
            }
            for (int kk = 0; kk < 12; kk++) {
                short8 xb[4], wvf[2];
                #pragma unroll
                for (int t = 0; t < 4; t++) xb[t] = *(const short8*)&X[xoff[t] + kk * 32];
                #pragma unroll
                for (int mt = 0; mt < 2; mt++)
                    wvf[mt] = *(const short8*)(wvp + (size_t)(16 * mt) * 384 + kk * 32);
                __builtin_amdgcn_s_setprio(1);
                #pragma unroll
                for (int mt = 0; mt < 4; mt++)
                    #pragma unroll
                    for (int nt = 0; nt < 2; nt++)
                        va[mt][nt] = __builtin_amdgcn_mfma_f32_16x16x32_bf16(xb[mt], wvf[nt], va[mt][nt], 0, 0, 0);
                __builtin_amdgcn_s_setprio(0);
            }
            #pragma unroll
            for (int nt = 0; nt < 2; nt++) {
                unsigned int pv[4][2];
                #pragma unroll
                for (int mt = 0; mt < 4; mt++) {
                    pv[mt][0] = pkbf(va[mt][nt][0], va[mt][nt][1]);
                    pv[mt][1] = pkbf(va[mt][nt][2], va[mt][nt][3]);
                }
                vf[0][nt] = repack(pv[0], pv[1], lid, g);
                vf[1][nt] = repack(pv[2], pv[3], lid, g);
            }
        }

        // ---- S^T = K·Q^T : D[k-tok][q-tok]  (16 MFMA, K=32) ----
        f32x4 S[4][4];  // [kt][qt]
        __builtin_amdgcn_s_setprio(1);
        #pragma unroll
        for (int kt = 0; kt < 4; kt++)
            #pragma unroll
            for (int qt = 0; qt < 4; qt++)
                S[kt][qt] = __builtin_amdgcn_mfma_f32_16x16x32_bf16(kf[kt], qf[qt], (f32x4){0.f, 0.f, 0.f, 0.f}, 0, 0, 0);
        __builtin_amdgcn_s_setprio(0);

        // ---- bias (mask + rpb, both L2-resident) + softmax over k; normalize P ----
        const float* mwp = Mw + (size_t)w64 * 4096;
        const float* rhp = Rh + (size_t)h * 4096;
        short8 pf[4][2];
        #pragma unroll
        for (int qt = 0; qt < 4; qt++) {
            #pragma unroll
            for (int kt = 0; kt < 4; kt++) {
                int off = (16 * qt + lid) * 64 + 16 * kt + 4 * g;
                S[kt][qt] += *(const f32x4*)(mwp + off) + *(const f32x4*)(rhp + off);
            }
            float mx = S[0][qt][0];
            #pragma unroll
            for (int kt = 0; kt < 4; kt++)
                #pragma unroll
                for (int r = 0; r < 4; r++) mx = fmaxf(mx, S[kt][qt][r]);
            mx = fmaxf(mx, __shfl_xor(mx, 16));
            mx = fmaxf(mx, __shfl_xor(mx, 32));
            float sm = 0.f;
            #pragma unroll
            for (int kt = 0; kt < 4; kt++)
                #pragma unroll
                for (int r = 0; r < 4; r++) {
                    float e = __expf(S[kt][qt][r] - mx);
                    S[kt][qt][r] = e; sm += e;
                }
            sm += __shfl_xor(sm, 16);
            sm += __shfl_xor(sm, 32);
            float rv = 1.0f / sm;
            unsigned int pp[4][2];
            #pragma unroll
            for (int kt = 0; kt < 4; kt++) {
                pp[kt][0] = pkbf(S[kt][qt][0] * rv, S[kt][qt][1] * rv);
                pp[kt][1] = pkbf(S[kt][qt][2] * rv, S[kt][qt][3] * rv);
            }
            pf[qt][0] = repack(pp[0], pp[1], lid, g);
            pf[qt][1] = repack(pp[2], pp[3], lid, g);
        }

        // ---- O^T = V^T·P^T : D[d][q-tok]  (operand-swapped PV) ----
        f32x4 OT[2][4];  // [dt][qt]: col = q-token = lid, row = d = 16dt+4g+r
        #pragma unroll
        for (int dt = 0; dt < 2; dt++)
            #pragma unroll
            for (int qt = 0; qt < 4; qt++) OT[dt][qt] = (f32x4){0.f,0.f,0.f,0.f};
        __builtin_amdgcn_s_setprio(1);
        #pragma unroll
        for (int kb = 0; kb < 2; kb++)
            #pragma unroll
            for (int dt = 0; dt < 2; dt++)
                #pragma unroll
                for (int qt = 0; qt < 4; qt++)
                    OT[dt][qt] = __builtin_amdgcn_mfma_f32_16x16x32_bf16(vf[kb][dt], pf[qt][kb], OT[dt][qt], 0, 0, 0);
        __builtin_amdgcn_s_setprio(0);

        // ---- store AO bf16 [head][token][32 d]: 8B per lane, contiguous full lines ----
        #pragma unroll
        for (int qt = 0; qt < 4; qt++) {
            int token = 16 * qt + lid;
            if (token < NTOK) {
                #pragma unroll
                for (int dt = 0; dt < 2; dt++) {
                    unsigned int lo = pkbf(OT[dt][qt][0], OT[dt][qt][1]);
                    unsigned int hi = pkbf(OT[dt][qt][2], OT[dt][qt][3]);
                    *(uint2*)(aow + (h * NTOK + token) * 32 + 16 * dt + 4 * g) = make_uint2(lo, hi);
                }
            }
        }
    }

    __threadfence_block();
    __syncthreads();

    // ---- proj: [49x384] @ Wt_proj + b; wave owns 96 cols; A-frags from AO scratch ----
    {
        const int c0 = wv * 96;
        f32x4 acc[4][6];
        #pragma unroll
        for (int nt = 0; nt < 6; nt++) {
            float bv = bproj[c0 + nt * 16 + lid];
            #pragma unroll
            for (int mt = 0; mt < 4; mt++) acc[mt][nt] = (f32x4){bv, bv, bv, bv};
        }
        #pragma unroll
        for (int kk = 0; kk < 12; kk++) {   // kk == head index; k = kk*32 + g*8 ..
            short8 a[4], bf[6];
            #pragma unroll
            for (int mt = 0; mt < 4; mt++) {
                int row = lid + 16 * mt;
                if (row > 48) row = 48;
                a[mt] = *(const short8*)(aow + (kk * NTOK + row) * 32 + g * 8);
            }
            #pragma unroll
            for (int nt = 0; nt < 6; nt++)
                bf[nt] = *(const short8*)(wtp + (size_t)(c0 + nt * 16 + lid) * 384 + kk * 32 + g * 8);
            __builtin_amdgcn_s_setprio(1);
            #pragma unroll
            for (int mt = 0; mt < 4; mt++)
                #pragma unroll
                for (int nt = 0; nt < 6; nt++)
                    acc[mt][nt] = __builtin_amdgcn_mfma_f32_16x16x32_bf16(a[mt], bf[nt], acc[mt][nt], 0, 0, 0);
            __builtin_amdgcn_s_setprio(0);
        }
        __syncthreads();   // all AO reads complete before in-place fp32 stores
        float* outb = out + (size_t)b * 18816;
        #pragma unroll
        for (int mt = 0; mt < 4; mt++)
            #pragma unroll
            for (int nt = 0; nt < 6; nt++)
                #pragma unroll
                for (int r = 0; r < 4; r++) {
                    int n = g * 4 + r + 16 * mt;
                    if (n < NTOK)
                        outb[n * 384 + c0 + nt * 16 + lid] = acc[mt][nt][r];
                }
    }
}

extern "C" void kernel_launch(void* const* d_in, const int* in_sizes, int n_in,
                              void* d_out, int out_size, void* d_ws, size_t ws_size,
                              hipStream_t stream) {
    const float* x      = (const float*)d_in[0];
    const float* mask   = (const float*)d_in[1];
    const float* qkv_w  = (const float*)d_in[2];
    const float* qkv_b  = (const float*)d_in[3];
    const float* rpb    = (const float*)d_in[4];
    const float* proj_w = (const float*)d_in[5];
    const float* proj_b = (const float*)d_in[6];
    unsigned char* ws = (unsigned char*)d_ws;

    wa_prep<<<dim3(1024), dim3(256), 0, stream>>>(mask, qkv_w, qkv_b, rpb, proj_w, ws);
    wa_main<<<dim3(NB), dim3(256), 0, stream>>>(x, proj_b, ws, (float*)d_out);
}